// Round 3
// baseline (3113.139 us; speedup 1.0000x reference)
//
#include <hip/hip_runtime.h>
#include <hip/hip_bf16.h>

#define Bsz  256
#define Tlen 2048
#define IN   128
#define H    64
#define XS   (IN/4)   // 32-elem x slice per thread
#define HS   (H/4)    // 16-elem h slice per thread

// K-split-4 @ 256 threads, 1 wave/SIMD:
//   256 threads = 64 h-indices (j = tid>>2) x 4 K-slices (q = tid&3).
//   vs round 2 (512 thr, K-split-8): same FMA issue per SIMD, but all
//   REPLICATED work (combine/unpack/reduce/loop) halves per SIMD, and the
//   weight file (320 f32/thread) fits the 1-wave/SIMD unified VGPR+AGPR
//   budget with __launch_bounds__(256,1).
//   Quad all-reduce = 2 DPP steps (xor1, xor2). Activation-select: lane q
//   activates only gate q via tanh(v)=2*sigm(2v)-1 (uniform, per-lane
//   consts), then 4 quad_perm DPP broadcasts distribute i,f,g,o ->
//   transcendentals cut 20 -> 8 per thread-step. c replicated across the
//   quad stays bit-identical (inputs all come from broadcasts).

typedef float v2f __attribute__((ext_vector_type(2)));

static __device__ __forceinline__ float bfbits2f(unsigned int u16) {
    union { unsigned int i; float f; } v; v.i = u16 << 16; return v.f;
}
static __device__ __forceinline__ v2f unpack_v2(unsigned int u) {
    union { unsigned int i; float f; } a, b;
    a.i = u << 16; b.i = u & 0xFFFF0000u;
    v2f r; r.x = a.f; r.y = b.f; return r;
}
static __device__ __forceinline__ v2f mkv2(float a, float b) { v2f r; r.x = a; r.y = b; return r; }
static __device__ __forceinline__ v2f fma2(v2f a, v2f b, v2f c) {
    return __builtin_elementwise_fma(a, b, c);
}

// Dtype sniff: W_ih1 ~ U(-1/8,1/8). bf16 mode: BOTH halves of every dword
// decode to |v|<=0.125. fp32 mode: low half is random mantissa bits ->
// P(all 32 dwords pass) ~ 1e-10. Deterministic.
static __device__ __forceinline__ int detect_bf16(const unsigned int* w) {
    int ok = 1;
#pragma unroll
    for (int i = 0; i < 32; ++i) {
        unsigned int u = w[i];
        float lo = bfbits2f(u & 0xFFFFu);
        float hi = bfbits2f(u >> 16);
        ok &= (fabsf(lo) <= 0.1251f) & (fabsf(hi) <= 0.1251f);
    }
    return ok;
}

template<bool BF>
static __device__ __forceinline__ float ld1(const void* p, size_t i) {
    if (BF) return bfbits2f(((const unsigned short*)p)[i]);
    else    return ((const float*)p)[i];
}

template<bool BF, int N>
static __device__ __forceinline__ void load_slice(v2f* dst, const void* src, size_t off) {
    if (BF) {
        const uint4* p = (const uint4*)((const unsigned short*)src + off);
#pragma unroll
        for (int i = 0; i < N / 8; ++i) {
            uint4 qd = p[i];
            dst[4*i+0] = unpack_v2(qd.x);
            dst[4*i+1] = unpack_v2(qd.y);
            dst[4*i+2] = unpack_v2(qd.z);
            dst[4*i+3] = unpack_v2(qd.w);
        }
    } else {
        const float4* p = (const float4*)((const float*)src + off);
#pragma unroll
        for (int i = 0; i < N / 4; ++i) {
            float4 qd = p[i];
            dst[2*i+0] = mkv2(qd.x, qd.y);
            dst[2*i+1] = mkv2(qd.z, qd.w);
        }
    }
}

static __device__ __forceinline__ float fast_rcp(float x) { return __builtin_amdgcn_rcpf(x); }
// tanh via exp; saturates for |x| large
static __device__ __forceinline__ float tanh_f(float x){
    float e = __expf(2.0f * x);
    return fmaf(-2.0f, fast_rcp(e + 1.0f), 1.0f);
}

// DPP helpers. 0xB1 = quad_perm xor1, 0x4E = quad_perm xor2.
template<int CTRL>
static __device__ __forceinline__ float dpp_sum_step(float x) {
    union { float f; int i; } u, v;
    u.f = x;
    v.i = __builtin_amdgcn_update_dpp(0, u.i, CTRL, 0xF, 0xF, true);
    return x + v.f;
}
static __device__ __forceinline__ float dpp4_allsum(float x) {
    x = dpp_sum_step<0xB1>(x);
    x = dpp_sum_step<0x4E>(x);
    return x;
}
// quad broadcast: all 4 lanes of a quad get lane L's value
template<int CTRL>
static __device__ __forceinline__ float qbcast(float x) {
    union { float f; int i; } u, v;
    u.f = x;
    v.i = __builtin_amdgcn_update_dpp(0, u.i, CTRL, 0xF, 0xF, true);
    return v.f;
}

// Combine: lane q activates gate q only (sigm for q!=2, tanh via
// 2*sigm(2v)-1 for q==2, selected by uniform per-lane consts), then quad
// broadcasts. All quad lanes end with identical c and returned h.
static __device__ __forceinline__ float lstm_combine(
    float r0, float r1, float r2, float r3,
    int q, float bown, float sc1, float sc2, float off, float& c)
{
    float own = (q == 0 ? r0 : q == 1 ? r1 : q == 2 ? r2 : r3) + bown;
    float s   = fast_rcp(1.0f + __expf(-(own * sc1)));
    float act = fmaf(s, sc2, off);
    float i_ = qbcast<0x00>(act);
    float f_ = qbcast<0x55>(act);
    float g_ = qbcast<0xAA>(act);
    float o_ = qbcast<0xFF>(act);
    c = fmaf(f_, c, i_ * g_);
    return o_ * tanh_f(c);
}

struct alignas(16) SharedMem {
    float h1[2][H];        // double-buffered layer-1 hidden
    float h2[2][H];        // double-buffered layer-2 hidden
    float hist[H][H + 1];  // h2 history for chunked head (+1 pad)
};

template<bool BF>
static __device__ void lstm_core(SharedMem* sm,
    const void* x,    const void* Wih1, const void* Whh1,
    const void* bih1, const void* bhh1, const void* Wih2,
    const void* Whh2, const void* bih2, const void* bhh2,
    const void* Wout, const void* bout, void* outp,
    int b, int tid)
{
    const int q = tid & 3;    // K-slice (lane bits 0-1)
    const int j = tid >> 2;   // h-index 0..63

    // ---- per-thread weight slices: 320 f32 (VGPR+AGPR unified file) ----
    v2f wx1[4][XS/2], wh1[4][HS/2], wx2[4][HS/2], wh2[4][HS/2];
#pragma unroll
    for (int a = 0; a < 4; ++a) {
        const int g = a * H + j;                      // torch gate order i,f,g,o
        load_slice<BF, XS>(wx1[a], Wih1, (size_t)g * IN + q * XS);
        load_slice<BF, HS>(wh1[a], Whh1, (size_t)g * H  + q * HS);
        load_slice<BF, HS>(wx2[a], Wih2, (size_t)g * H  + q * HS);
        load_slice<BF, HS>(wh2[a], Whh2, (size_t)g * H  + q * HS);
    }
    // lane q only activates gate q -> only that gate's bias is needed
    const int gq = q * H + j;
    const float bown1 = ld1<BF>(bih1, gq) + ld1<BF>(bhh1, gq);
    const float bown2 = ld1<BF>(bih2, gq) + ld1<BF>(bhh2, gq);
    // activation-select constants: q==2 is the tanh gate (g)
    const float sc1 = (q == 2) ? 2.0f : 1.0f;
    const float sc2 = (q == 2) ? 2.0f : 1.0f;
    const float off = (q == 2) ? -1.0f : 0.0f;

    float wout_r[HS];
#pragma unroll
    for (int i = 0; i < HS; ++i) wout_r[i] = ld1<BF>(Wout, q * HS + i);
    const float boutv = ld1<BF>(bout, 0);

    if (tid < H) sm->h2[1][tid] = 0.f;     // h2[-1] lives in buffer (0+1)&1

    // ---- x slice access (direct global; 4 distinct 16-lane-shared lines) ----
    const unsigned short* xb_b = (const unsigned short*)x + (size_t)b * Tlen * IN + q * XS;
    const float*          xb_f = (const float*)x          + (size_t)b * Tlen * IN + q * XS;

    uint4  rb[4];
    float4 rf[8];
    v2f xc[XS/2];

    auto load_x = [&](int t) {
        if (BF) {
            const uint4* p = (const uint4*)(xb_b + (size_t)t * IN);
#pragma unroll
            for (int i = 0; i < 4; ++i) rb[i] = p[i];
        } else {
            const float4* p = (const float4*)(xb_f + (size_t)t * IN);
#pragma unroll
            for (int i = 0; i < 8; ++i) rf[i] = p[i];
        }
    };
    auto unpack_x = [&]() {
        if (BF) {
#pragma unroll
            for (int i = 0; i < 4; ++i) {
                xc[4*i+0] = unpack_v2(rb[i].x);
                xc[4*i+1] = unpack_v2(rb[i].y);
                xc[4*i+2] = unpack_v2(rb[i].z);
                xc[4*i+3] = unpack_v2(rb[i].w);
            }
        } else {
#pragma unroll
            for (int i = 0; i < 8; ++i) {
                xc[2*i+0] = mkv2(rf[i].x, rf[i].y);
                xc[2*i+1] = mkv2(rf[i].z, rf[i].w);
            }
        }
    };

    float c1 = 0.f, c2 = 0.f;   // replicated across the quad (bit-identical)

    // ---- prologue: phase1(0) with h1[-1]=0 ----
    load_x(0); unpack_x();
    load_x(1);                       // rb := x_1
    {
        v2f a0 = mkv2(0.f, 0.f), a1 = a0, a2 = a0, a3 = a0;
#pragma unroll
        for (int p = 0; p < XS/2; ++p) {
            a0 = fma2(wx1[0][p], xc[p], a0);
            a1 = fma2(wx1[1][p], xc[p], a1);
            a2 = fma2(wx1[2][p], xc[p], a2);
            a3 = fma2(wx1[3][p], xc[p], a3);
        }
        float r0 = dpp4_allsum(a0.x + a0.y);
        float r1 = dpp4_allsum(a1.x + a1.y);
        float r2 = dpp4_allsum(a2.x + a2.y);
        float r3 = dpp4_allsum(a3.x + a3.y);
        float h1n = lstm_combine(r0, r1, r2, r3, q, bown1, sc1, sc2, off, c1);
        if (q == 0) sm->h1[0][j] = h1n;
    }
    __syncthreads();                                // h1[0], h2-zero visible

    // ---- main loop: one barrier/step; region(t) = phase2(t) + phase1(t+1) ----
    for (int t = 0; t < Tlen; ++t) {
        // LDS reads issue first; latency hidden by x-unpack + Wih1*x below
        const float4* h1p = (const float4*)&sm->h1[t & 1][q * HS];
        const float4* h2p = (const float4*)&sm->h2[(t + 1) & 1][q * HS];
        float4 nA = h1p[0], nB = h1p[1], nC = h1p[2], nD = h1p[3]; // h1[t]
        float4 oA = h2p[0], oB = h2p[1], oC = h2p[2], oD = h2p[3]; // h2[t-1]

        const bool havex = (t + 1 < Tlen);          // uniform
        if (havex) unpack_x();                      // xc := x_{t+1}
        if (t + 2 < Tlen) load_x(t + 2);            // rb := x_{t+2}

        // phase1(t+1) x-part: LDS-independent filler work
        v2f a0 = mkv2(0.f, 0.f), a1 = a0, a2 = a0, a3 = a0;
        if (havex) {
#pragma unroll
            for (int p = 0; p < XS/2; ++p) {
                a0 = fma2(wx1[0][p], xc[p], a0);
                a1 = fma2(wx1[1][p], xc[p], a1);
                a2 = fma2(wx1[2][p], xc[p], a2);
                a3 = fma2(wx1[3][p], xc[p], a3);
            }
        }

        v2f nv[HS/2] = { mkv2(nA.x,nA.y), mkv2(nA.z,nA.w), mkv2(nB.x,nB.y), mkv2(nB.z,nB.w),
                         mkv2(nC.x,nC.y), mkv2(nC.z,nC.w), mkv2(nD.x,nD.y), mkv2(nD.z,nD.w) };
        v2f ov[HS/2] = { mkv2(oA.x,oA.y), mkv2(oA.z,oA.w), mkv2(oB.x,oB.y), mkv2(oB.z,oB.w),
                         mkv2(oC.x,oC.y), mkv2(oC.z,oC.w), mkv2(oD.x,oD.y), mkv2(oD.z,oD.w) };

        // phase2(t) gate partials
        v2f e0 = mkv2(0.f, 0.f), e1 = e0, e2 = e0, e3 = e0;
#pragma unroll
        for (int p = 0; p < HS/2; ++p) {
            e0 = fma2(wx2[0][p], nv[p], e0);
            e1 = fma2(wx2[1][p], nv[p], e1);
            e2 = fma2(wx2[2][p], nv[p], e2);
            e3 = fma2(wx2[3][p], nv[p], e3);
        }
#pragma unroll
        for (int p = 0; p < HS/2; ++p) {
            e0 = fma2(wh2[0][p], ov[p], e0);
            e1 = fma2(wh2[1][p], ov[p], e1);
            e2 = fma2(wh2[2][p], ov[p], e2);
            e3 = fma2(wh2[3][p], ov[p], e3);
        }

        // phase1(t+1) h-part (same nv) — independent of e-reduce
        if (havex) {
#pragma unroll
            for (int p = 0; p < HS/2; ++p) {
                a0 = fma2(wh1[0][p], nv[p], a0);
                a1 = fma2(wh1[1][p], nv[p], a1);
                a2 = fma2(wh1[2][p], nv[p], a2);
                a3 = fma2(wh1[3][p], nv[p], a3);
            }
        }

        // combine 2 (quad-replicated)
        {
            float s0 = dpp4_allsum(e0.x + e0.y);
            float s1 = dpp4_allsum(e1.x + e1.y);
            float s2 = dpp4_allsum(e2.x + e2.y);
            float s3 = dpp4_allsum(e3.x + e3.y);
            float h2n = lstm_combine(s0, s1, s2, s3, q, bown2, sc1, sc2, off, c2);
            if (q == 0) {
                sm->h2[t & 1][j] = h2n;
                sm->hist[j][t & 63] = h2n;
            }
        }

        // combine 1 (h1[t+1])
        if (havex) {
            float r0 = dpp4_allsum(a0.x + a0.y);
            float r1 = dpp4_allsum(a1.x + a1.y);
            float r2 = dpp4_allsum(a2.x + a2.y);
            float r3 = dpp4_allsum(a3.x + a3.y);
            float h1n = lstm_combine(r0, r1, r2, r3, q, bown1, sc1, sc2, off, c1);
            if (q == 0) sm->h1[(t + 1) & 1][j] = h1n;
        }

        // head projection once per 64-step chunk
        if ((t & 63) == 63) {
            __syncthreads();                        // all hist writes visible
            const int tt = j;                       // time column 0..63
            float s = 0.f;
#pragma unroll
            for (int i = 0; i < HS; ++i)
                s = fmaf(wout_r[i], sm->hist[q * HS + i][tt], s);
            s = dpp4_allsum(s);
            if (q == 0) {
                s += boutv;
                s = fminf(fmaxf(s, 0.f), 1.f);
                const size_t oi = (size_t)b * Tlen + (t - 63) + tt;
                if (BF) ((__hip_bfloat16*)outp)[oi] = __float2bfloat16(s);
                else    ((float*)outp)[oi] = s;
            }
            // hist col reuse is 64 steps away; end-of-region barrier suffices
        }

        __syncthreads();                            // the single per-step barrier
    }
}

__global__ __launch_bounds__(256, 1)
void lstm2_fused(const void* __restrict__ x,    const void* __restrict__ Wih1,
                 const void* __restrict__ Whh1, const void* __restrict__ bih1,
                 const void* __restrict__ bhh1, const void* __restrict__ Wih2,
                 const void* __restrict__ Whh2, const void* __restrict__ bih2,
                 const void* __restrict__ bhh2, const void* __restrict__ Wout,
                 const void* __restrict__ bout, void* __restrict__ outp)
{
    __shared__ SharedMem sm;
    __shared__ int mode_bf;
    const int tid = threadIdx.x;
    if (tid == 0) mode_bf = detect_bf16((const unsigned int*)Wih1);
    __syncthreads();

    if (mode_bf)
        lstm_core<true >(&sm, x, Wih1, Whh1, bih1, bhh1, Wih2, Whh2, bih2, bhh2,
                         Wout, bout, outp, blockIdx.x, tid);
    else
        lstm_core<false>(&sm, x, Wih1, Whh1, bih1, bhh1, Wih2, Whh2, bih2, bhh2,
                         Wout, bout, outp, blockIdx.x, tid);
}

extern "C" void kernel_launch(void* const* d_in, const int* in_sizes, int n_in,
                              void* d_out, int out_size, void* d_ws, size_t ws_size,
                              hipStream_t stream)
{
    (void)in_sizes; (void)n_in; (void)d_ws; (void)ws_size; (void)out_size;
    lstm2_fused<<<dim3(Bsz), dim3(256), 0, stream>>>(
        d_in[0], d_in[1], d_in[2], d_in[3], d_in[4], d_in[5],
        d_in[6], d_in[7], d_in[8], d_in[9], d_in[10], d_out);
}